// Round 7
// baseline (154.577 us; speedup 1.0000x reference)
//
#include <hip/hip_runtime.h>
#include <math.h>

#define NN 30000
#define DIST_C 5.0f
#define EPS_C 1e-6f
#define SCALE_C 0.17677669529663687f  // 1/sqrt(32)

// workspace float offsets
#define WS_ZMIN 0      // 16 f (plain floats)
#define WS_ZMAX 16     // 16 f
#define WS_ZSUM 32     // 32 f  [b*2+s]
#define WS_T    64     // 8192 f [b*512 + (s*8+h)*32 + d]
#define WS_PK   8256   // 256 f [h*32+d]
#define WS_WC   8512   // 1024 f [d*32+e]

#define NPT 16         // nodes per tile; 30000/16 = 1875 blocks, no tail

__device__ __forceinline__ float silu(float x) { return x / (1.0f + expf(-x)); }

// edge[s][k] = sin(bw_k*x_s)/(x_s+eps); bw_k=(k+1)*bw0. Chebyshev recurrence:
// s_{k+1} = 2cos(th)*s_k - s_{k-1}.
__device__ __forceinline__ void bessel_edges(float bw0, float x0, float x1, float edge[2][8]) {
    float xs[2]; xs[0] = x0; xs[1] = x1;
#pragma unroll
    for (int s = 0; s < 2; ++s) {
        float x = xs[s];
        float inv = 1.0f / (x + EPS_C);
        float th = bw0 * x;
        float c2 = 2.0f * cosf(th);
        float skm1 = 0.0f;
        float sk = sinf(th);
#pragma unroll
        for (int k = 0; k < 8; ++k) {
            edge[s][k] = sk * inv;
            float nx = c2 * sk - skm1;
            skm1 = sk; sk = nx;
        }
    }
}

// ---------------------------------------------------------------- K1: pre
// blocks 0-15: per-batch zminmax (binary-search bounds + scan, plain writes)
// block 16: Pk chain; block 17: Wc; blocks 18-33: zero T + ZSUM.
__global__ __launch_bounds__(256) void k_pre(const float* __restrict__ pos,
                                             const int* __restrict__ batch,
                                             const float* __restrict__ init_dummy,
                                             const float* __restrict__ Wq_dummy,
                                             const float* __restrict__ Wdot,
                                             const float* __restrict__ W2_kd,
                                             const float* __restrict__ Wq_graph,
                                             float* __restrict__ ws) {
    int t = threadIdx.x, blk = blockIdx.x;
    if (blk < 16) {
        __shared__ int bnd2[2];
        __shared__ float r[8];
        if (t < 2) {
            int target = blk + t;
            int lo = 0, hi = NN;
            while (lo < hi) { int mid = (lo + hi) >> 1; if (batch[mid] < target) lo = mid + 1; else hi = mid; }
            bnd2[t] = lo;
        }
        __syncthreads();
        int s0 = bnd2[0], s1 = bnd2[1];
        float zmn = 3.4e38f, zmx = -3.4e38f;
        for (int i = s0 + t; i < s1; i += 256) {
            float v = pos[3 * i + 2];
            zmn = fminf(zmn, v); zmx = fmaxf(zmx, v);
        }
#pragma unroll
        for (int off = 1; off < 64; off <<= 1) {
            zmn = fminf(zmn, __shfl_xor(zmn, off, 64));
            zmx = fmaxf(zmx, __shfl_xor(zmx, off, 64));
        }
        if ((t & 63) == 0) { r[(t >> 6) * 2] = zmn; r[(t >> 6) * 2 + 1] = zmx; }
        __syncthreads();
        if (t == 0) {
            ws[WS_ZMIN + blk] = fminf(fminf(r[0], r[2]), fminf(r[4], r[6]));
            ws[WS_ZMAX + blk] = fmaxf(fmaxf(r[1], r[3]), fmaxf(r[5], r[7]));
        }
    } else if (blk == 16) {
        __shared__ float qv[32], qW[32];
        if (t < 32) {
            float acc = 0.f;
            for (int d = 0; d < 32; ++d) acc += init_dummy[d] * Wq_dummy[d * 32 + t];
            qv[t] = acc;
        }
        __syncthreads();
        if (t < 32) {
            float acc = 0.f;
            for (int e = 0; e < 32; ++e) acc += qv[e] * Wdot[e * 32 + t];
            qW[t] = acc;
        }
        __syncthreads();
        int h = t >> 5, d = t & 31;
        float acc = 0.f;
        for (int e = 0; e < 32; ++e) acc += W2_kd[h * 1024 + d * 32 + e] * qW[e];
        ws[WS_PK + t] = acc;
    } else if (blk == 17) {
        for (int i = t; i < 1024; i += 256) {
            int d = i >> 5, e = i & 31;
            float acc = 0.f;
            for (int m = 0; m < 32; ++m) acc += Wq_graph[d * 32 + m] * Wdot[m * 32 + e];
            ws[WS_WC + i] = acc;
        }
    } else {
        int idx = blk - 18;
        ws[WS_T + idx * 512 + t] = 0.f;
        ws[WS_T + idx * 512 + 256 + t] = 0.f;
        if (idx == 0 && t < 32) ws[WS_ZSUM + t] = 0.f;
    }
}

// ---------------------------------------------------------------- K2: phase 1
// 128 threads, 16 nodes/block (8 threads per node): t = li*8 + g.
// Fl row stride 36 floats; Lw row stride 17.
__global__ __launch_bounds__(128) void k_phase1(const float* __restrict__ pos,
                                                const int* __restrict__ batch,
                                                const float* __restrict__ nf,
                                                const float* __restrict__ bw,
                                                const float* __restrict__ W1_kd,
                                                const float* __restrict__ W1_vd,
                                                float* __restrict__ ws) {
    __shared__ __align__(16) float Fl[NPT * 36];
    __shared__ float Lw[NPT * 17];
    __shared__ int   Lb[NPT];
    __shared__ __align__(16) float Pk[256];
    __shared__ float W1kd[64], W1vd[64], zsl[32];
    int t = threadIdx.x;
    if (t < 64) { W1kd[t] = W1_kd[t]; W1vd[t] = W1_vd[t]; }
    Pk[t] = ws[WS_PK + t];
    Pk[t + 128] = ws[WS_PK + t + 128];
    if (t < 32) zsl[t] = 0.f;

    int li = t >> 3, g = t & 7;
    int n0 = blockIdx.x * NPT;
    int n = n0 + li;
    int b = batch[n];
    float4 fv4 = ((const float4*)nf)[n * 8 + g];
    ((float4*)(Fl + li * 36))[g] = fv4;
    if (g == 0) Lb[li] = b;
    __syncthreads();

    {
        float z = pos[3 * n + 2];
        float zminb = ws[WS_ZMIN + b];
        float zmaxb = ws[WS_ZMAX + b];
        float edge[2][8];
        bessel_edges(bw[0], z - zminb + DIST_C, zmaxb + DIST_C - z, edge);

        float up[8];
        const float4* Pk4 = (const float4*)Pk;
#pragma unroll
        for (int h = 0; h < 8; ++h) {
            float4 p = Pk4[h * 8 + g];
            up[h] = fv4.x * p.x + fv4.y * p.y + fv4.z * p.z + fv4.w * p.w;
        }
        float kd0, kd1;
        {
            float p0 = 0.f, p1 = 0.f;
#pragma unroll
            for (int k = 0; k < 8; ++k) {
                float w = W1kd[k * 8 + g];
                p0 += edge[0][k] * w;
                p1 += edge[1][k] * w;
            }
            kd0 = silu(p0); kd1 = silu(p1);
        }
        int lanebase = (t & 63) & 56;
        float sp0 = 0.f, sp1 = 0.f;
#pragma unroll
        for (int h = 0; h < 8; ++h) {
            sp0 += __shfl(kd0, lanebase + h, 64) * up[h];
            sp1 += __shfl(kd1, lanebase + h, 64) * up[h];
        }
#pragma unroll
        for (int m = 1; m < 8; m <<= 1) {
            sp0 += __shfl_xor(sp0, m, 64);
            sp1 += __shfl_xor(sp1, m, 64);
        }
        float ev0 = expf(sp0 * SCALE_C);
        float ev1 = expf(sp1 * SCALE_C);
        if (g == 0) {
            atomicAdd(&zsl[b * 2 + 0], ev0);
            atomicAdd(&zsl[b * 2 + 1], ev1);
        }
        float q0 = 0.f, q1 = 0.f;
#pragma unroll
        for (int k = 0; k < 8; ++k) {
            float w = W1vd[k * 8 + g];
            q0 += edge[0][k] * w;
            q1 += edge[1][k] * w;
        }
        Lw[li * 17 + g]     = ev0 * silu(q0);
        Lw[li * 17 + 8 + g] = ev1 * silu(q1);
    }
    __syncthreads();
    if (t < 32 && zsl[t] != 0.f) atomicAdd(&ws[WS_ZSUM + t], zsl[t]);

    // segment outer-product reduce: T[b][sh][d] += Lw[i][sh] * Fl[i][d]
    // thread owns (sh = t&15, dq = t>>4): one float4 accumulator per segment.
    int bf = Lb[0], bl = Lb[NPT - 1];
    int sh = t & 15, dq = t >> 4;
    const float4* Fl4 = (const float4*)Fl;
    for (int b2 = bf; b2 <= bl; ++b2) {
        float4 a = make_float4(0.f, 0.f, 0.f, 0.f);
        for (int i = 0; i < NPT; ++i) {
            if (Lb[i] != b2) continue;
            float w = Lw[i * 17 + sh];
            float4 x = Fl4[i * 9 + dq];
            a.x += w * x.x; a.y += w * x.y; a.z += w * x.z; a.w += w * x.w;
        }
        float* Tb = ws + WS_T + b2 * 512 + sh * 32 + dq * 4;
        atomicAdd(&Tb[0], a.x); atomicAdd(&Tb[1], a.y);
        atomicAdd(&Tb[2], a.z); atomicAdd(&Tb[3], a.w);
    }
}

// ---------------------------------------------------------------- K3: B (redundant, in-LDS) + final
// 128 threads, 16 nodes/block. T complete at entry (kernel boundary = sync).
// scr0: Tl then AK; scr1: part then AV (LDS overlay). Single-slot fast path
// when the tile doesn't straddle a batch boundary (1860/1875 blocks).
__global__ __launch_bounds__(128) void k_fin(const float* __restrict__ pos,
                                             const int* __restrict__ batch,
                                             const float* __restrict__ nf,
                                             const float* __restrict__ bw,
                                             const float* __restrict__ W1_kg,
                                             const float* __restrict__ W1_vg,
                                             const float* __restrict__ init_dummy,
                                             const float* __restrict__ W2_vd,
                                             const float* __restrict__ W2_kg,
                                             const float* __restrict__ W2_vg,
                                             const float* __restrict__ ws,
                                             float* __restrict__ out) {
    __shared__ __align__(16) float Wc[1024];
    __shared__ __align__(16) float Fl[NPT * 36];
    __shared__ int   Lb[NPT];
    __shared__ float W1kg[64], W1vg[64];
    __shared__ __align__(16) float scr0[2][512];  // Tl -> AK
    __shared__ __align__(16) float scr1[2][512];  // part -> AV
    __shared__ float dn[2][64];                   // [slot][s*32+d]

    int t = threadIdx.x;
    int li = t >> 3, g = t & 7;
    int lanebase = (t & 63) & 56;
    {
        const float4* Wg4 = (const float4*)(ws + WS_WC);
        float4* Wc4w = (float4*)Wc;
        Wc4w[t] = Wg4[t];
        Wc4w[t + 128] = Wg4[t + 128];
    }
    if (t < 64) { W1kg[t] = W1_kg[t]; W1vg[t] = W1_vg[t]; }

    int n0 = blockIdx.x * NPT;
    int n = n0 + li;
    int b = batch[n];
    float4 fv4 = ((const float4*)nf)[n * 8 + g];
    ((float4*)(Fl + li * 36))[g] = fv4;
    float z = pos[3 * n + 2];
    if (g == 0) Lb[li] = b;
    __syncthreads();
    int bf = Lb[0], bl = Lb[NPT - 1];
    int nseg = (bl != bf) ? 2 : 1;

    // stage T (512 f per slot, 4 loads/thread)
    for (int sl = 0; sl < nseg; ++sl) {
        const float* Tg = ws + WS_T + (sl ? bl : bf) * 512;
        scr0[sl][t]       = Tg[t];
        scr0[sl][t + 128] = Tg[t + 128];
        scr0[sl][t + 256] = Tg[t + 256];
        scr0[sl][t + 384] = Tg[t + 384];
    }
    __syncthreads();
    // part[sl][s*256 + h*32+e] = sum_d Tl[sl][s*256 + h*32+d] * W2_vd[h,d*32+e]
    for (int sl = 0; sl < nseg; ++sl) {
        for (int o = t; o < 256; o += 128) {
            int h = o >> 5, e = o & 31;
            float a0 = 0.f, a1 = 0.f;
            for (int d = 0; d < 32; ++d) {
                float w2 = W2_vd[h * 1024 + d * 32 + e];
                a0 += scr0[sl][h * 32 + d] * w2;
                a1 += scr0[sl][256 + h * 32 + d] * w2;
            }
            scr1[sl][o] = a0; scr1[sl][256 + o] = a1;
        }
    }
    __syncthreads();
    if (t < 64) {
        int s = t >> 5, dd = t & 31;
        float id = init_dummy[dd];
        for (int sl = 0; sl < nseg; ++sl) {
            int bb = sl ? bl : bf;
            float acc = 0.f;
            for (int h = 0; h < 8; ++h) acc += scr1[sl][s * 256 + h * 32 + dd];
            dn[sl][t] = id + acc / ws[WS_ZSUM + bb * 2 + s];
        }
    }
    __syncthreads();
    // AK -> scr0, AV -> scr1 (Tl/part dead after the dn sync)
    for (int sl = 0; sl < nseg; ++sl) {
        for (int o = t; o < 256; o += 128) {
            int h = o >> 5, e = o & 31;
            float k0 = 0.f, k1 = 0.f, v0 = 0.f, v1 = 0.f;
            for (int d = 0; d < 32; ++d) {
                float w2k = W2_kg[h * 1024 + d * 32 + e];
                float w2v = W2_vg[h * 1024 + d * 32 + e];
                float d0 = dn[sl][d], d1 = dn[sl][32 + d];
                k0 += d0 * w2k; k1 += d1 * w2k;
                v0 += d0 * w2v; v1 += d1 * w2v;
            }
            scr0[sl][o] = k0; scr0[sl][256 + o] = k1;
            scr1[sl][o] = v0; scr1[sl][256 + o] = v1;
        }
    }
    __syncthreads();

    int slot = (b == bf) ? 0 : 1;
    const float4* Ak4 = (const float4*)scr0[slot];
    const float4* Av4 = (const float4*)scr1[slot];
    const float4* Wc4 = (const float4*)Wc;

    float zminb = ws[WS_ZMIN + b];
    float zmaxb = ws[WS_ZMAX + b];
    float edge[2][8];
    bessel_edges(bw[0], z - zminb + DIST_C, zmaxb + DIST_C - z, edge);

    float sk0, sk1, sv0, sv1;
    {
        float pk0 = 0.f, pk1 = 0.f, pv0 = 0.f, pv1 = 0.f;
#pragma unroll
        for (int k = 0; k < 8; ++k) {
            float wk = W1kg[k * 8 + g];
            float wv = W1vg[k * 8 + g];
            pk0 += edge[0][k] * wk; pk1 += edge[1][k] * wk;
            pv0 += edge[0][k] * wv; pv1 += edge[1][k] * wv;
        }
        sk0 = silu(pk0); sk1 = silu(pk1);
        sv0 = silu(pv0); sv1 = silu(pv1);
    }
    float4 q4 = make_float4(0.f, 0.f, 0.f, 0.f);
    const float* myF = Fl + li * 36;
#pragma unroll
    for (int d = 0; d < 32; ++d) {
        float fd = myF[d];
        float4 w = Wc4[d * 8 + g];
        q4.x += fd * w.x; q4.y += fd * w.y; q4.z += fd * w.z; q4.w += fd * w.w;
    }
    float p0 = 0.f, p1 = 0.f;
#pragma unroll
    for (int h = 0; h < 8; ++h) {
        float4 a0 = Ak4[h * 8 + g];
        float4 a1 = Ak4[64 + h * 8 + g];
        float d0 = q4.x * a0.x + q4.y * a0.y + q4.z * a0.z + q4.w * a0.w;
        float d1 = q4.x * a1.x + q4.y * a1.y + q4.z * a1.z + q4.w * a1.w;
        p0 += __shfl(sk0, lanebase + h, 64) * d0;
        p1 += __shfl(sk1, lanebase + h, 64) * d1;
    }
#pragma unroll
    for (int m = 1; m < 8; m <<= 1) {
        p0 += __shfl_xor(p0, m, 64);
        p1 += __shfl_xor(p1, m, 64);
    }
    float sg0 = p0 * SCALE_C, sg1 = p1 * SCALE_C;
    float mx = fmaxf(sg0, sg1);
    float e0 = expf(sg0 - mx), e1 = expf(sg1 - mx);
    float inv = 1.0f / (e0 + e1);
    float ag0 = e0 * inv, ag1 = e1 * inv;

    float4 x4 = fv4;
#pragma unroll
    for (int h = 0; h < 8; ++h) {
        float w0 = ag0 * __shfl(sv0, lanebase + h, 64);
        float w1 = ag1 * __shfl(sv1, lanebase + h, 64);
        float4 a0 = Av4[h * 8 + g];
        float4 a1 = Av4[64 + h * 8 + g];
        x4.x += w0 * a0.x + w1 * a1.x;
        x4.y += w0 * a0.y + w1 * a1.y;
        x4.z += w0 * a0.z + w1 * a1.z;
        x4.w += w0 * a0.w + w1 * a1.w;
    }
    ((float4*)out)[n * 8 + g] = x4;
}

extern "C" void kernel_launch(void* const* d_in, const int* in_sizes, int n_in,
                              void* d_out, int out_size, void* d_ws, size_t ws_size,
                              hipStream_t stream) {
    const float* pos        = (const float*)d_in[0];
    const float* nf         = (const float*)d_in[1];
    const int*   batch      = (const int*)d_in[2];
    const float* bw         = (const float*)d_in[3];
    const float* init_dummy = (const float*)d_in[4];
    const float* Wq_dummy   = (const float*)d_in[5];
    const float* Wq_graph   = (const float*)d_in[6];
    const float* Wdot       = (const float*)d_in[7];
    const float* W1_kd      = (const float*)d_in[8];
    const float* W2_kd      = (const float*)d_in[9];
    const float* W1_vd      = (const float*)d_in[10];
    const float* W2_vd      = (const float*)d_in[11];
    const float* W1_kg      = (const float*)d_in[12];
    const float* W2_kg      = (const float*)d_in[13];
    const float* W1_vg      = (const float*)d_in[14];
    const float* W2_vg      = (const float*)d_in[15];
    float* ws  = (float*)d_ws;
    float* out = (float*)d_out;

    int nblk = NN / NPT;   // 1875 exactly
    hipLaunchKernelGGL(k_pre, dim3(34), dim3(256), 0, stream,
                       pos, batch, init_dummy, Wq_dummy, Wdot, W2_kd, Wq_graph, ws);
    hipLaunchKernelGGL(k_phase1, dim3(nblk), dim3(128), 0, stream,
                       pos, batch, nf, bw, W1_kd, W1_vd, ws);
    hipLaunchKernelGGL(k_fin, dim3(nblk), dim3(128), 0, stream,
                       pos, batch, nf, bw, W1_kg, W1_vg, init_dummy,
                       W2_vd, W2_kg, W2_vg, ws, out);
}

// Round 8
// 122.922 us; speedup vs baseline: 1.2575x; 1.2575x over previous
//
#include <hip/hip_runtime.h>
#include <math.h>

#define NN 30000
#define DIST_C 5.0f
#define EPS_C 1e-6f
#define SCALE_C 0.17677669529663687f  // 1/sqrt(32)

// workspace float offsets
#define WS_ZMIN 0      // 16 f (plain floats)
#define WS_ZMAX 16     // 16 f
#define WS_ZSUM 32     // 32 f  [b*2+s]
#define WS_T    64     // 8192 f [b*512 + (s*8+h)*32 + d]
#define WS_PK   8256   // 256 f [h*32+d]
#define WS_WC   8512   // 1024 f [d*32+e]
#define WS_AKG  9536   // 8192 f [b*512 + s*256 + h*32 + e]
#define WS_AVG  17728  // 8192 f

#define NPT 32         // nodes per tile (8 threads/node, 256-thread blocks)

__device__ __forceinline__ float silu(float x) { return x / (1.0f + expf(-x)); }

// edge[s][k] = sin(bw_k*x_s)/(x_s+eps); bw_k=(k+1)*bw0. Chebyshev recurrence:
// s_{k+1} = 2cos(th)*s_k - s_{k-1}.
__device__ __forceinline__ void bessel_edges(float bw0, float x0, float x1, float edge[2][8]) {
    float xs[2]; xs[0] = x0; xs[1] = x1;
#pragma unroll
    for (int s = 0; s < 2; ++s) {
        float x = xs[s];
        float inv = 1.0f / (x + EPS_C);
        float th = bw0 * x;
        float c2 = 2.0f * cosf(th);
        float skm1 = 0.0f;
        float sk = sinf(th);
#pragma unroll
        for (int k = 0; k < 8; ++k) {
            edge[s][k] = sk * inv;
            float nx = c2 * sk - skm1;
            skm1 = sk; sk = nx;
        }
    }
}

// ---------------------------------------------------------------- K1: pre
// blocks 0-15: per-batch zminmax; block 16: Pk chain; block 17: Wc;
// blocks 18-33: zero T + ZSUM.
__global__ __launch_bounds__(256) void k_pre(const float* __restrict__ pos,
                                             const int* __restrict__ batch,
                                             const float* __restrict__ init_dummy,
                                             const float* __restrict__ Wq_dummy,
                                             const float* __restrict__ Wdot,
                                             const float* __restrict__ W2_kd,
                                             const float* __restrict__ Wq_graph,
                                             float* __restrict__ ws) {
    int t = threadIdx.x, blk = blockIdx.x;
    if (blk < 16) {
        __shared__ int bnd2[2];
        __shared__ float r[8];
        if (t < 2) {
            int target = blk + t;
            int lo = 0, hi = NN;
            while (lo < hi) { int mid = (lo + hi) >> 1; if (batch[mid] < target) lo = mid + 1; else hi = mid; }
            bnd2[t] = lo;
        }
        __syncthreads();
        int s0 = bnd2[0], s1 = bnd2[1];
        float zmn = 3.4e38f, zmx = -3.4e38f;
        for (int i = s0 + t; i < s1; i += 256) {
            float v = pos[3 * i + 2];
            zmn = fminf(zmn, v); zmx = fmaxf(zmx, v);
        }
#pragma unroll
        for (int off = 1; off < 64; off <<= 1) {
            zmn = fminf(zmn, __shfl_xor(zmn, off, 64));
            zmx = fmaxf(zmx, __shfl_xor(zmx, off, 64));
        }
        if ((t & 63) == 0) { r[(t >> 6) * 2] = zmn; r[(t >> 6) * 2 + 1] = zmx; }
        __syncthreads();
        if (t == 0) {
            ws[WS_ZMIN + blk] = fminf(fminf(r[0], r[2]), fminf(r[4], r[6]));
            ws[WS_ZMAX + blk] = fmaxf(fmaxf(r[1], r[3]), fmaxf(r[5], r[7]));
        }
    } else if (blk == 16) {
        __shared__ float qv[32], qW[32];
        if (t < 32) {
            float acc = 0.f;
            for (int d = 0; d < 32; ++d) acc += init_dummy[d] * Wq_dummy[d * 32 + t];
            qv[t] = acc;
        }
        __syncthreads();
        if (t < 32) {
            float acc = 0.f;
            for (int e = 0; e < 32; ++e) acc += qv[e] * Wdot[e * 32 + t];
            qW[t] = acc;
        }
        __syncthreads();
        int h = t >> 5, d = t & 31;
        float acc = 0.f;
        for (int e = 0; e < 32; ++e) acc += W2_kd[h * 1024 + d * 32 + e] * qW[e];
        ws[WS_PK + t] = acc;
    } else if (blk == 17) {
        for (int i = t; i < 1024; i += 256) {
            int d = i >> 5, e = i & 31;
            float acc = 0.f;
            for (int m = 0; m < 32; ++m) acc += Wq_graph[d * 32 + m] * Wdot[m * 32 + e];
            ws[WS_WC + i] = acc;
        }
    } else {
        int idx = blk - 18;
        ws[WS_T + idx * 512 + t] = 0.f;
        ws[WS_T + idx * 512 + 256 + t] = 0.f;
        if (idx == 0 && t < 32) ws[WS_ZSUM + t] = 0.f;
    }
}

// ---------------------------------------------------------------- K2: phase 1
// 256 threads, 32 nodes/block (8 threads per node): t = li*8 + g.
// Fl row stride 36 floats; Lw row stride 17.
__global__ __launch_bounds__(256) void k_phase1(const float* __restrict__ pos,
                                                const int* __restrict__ batch,
                                                const float* __restrict__ nf,
                                                const float* __restrict__ bw,
                                                const float* __restrict__ W1_kd,
                                                const float* __restrict__ W1_vd,
                                                float* __restrict__ ws) {
    __shared__ __align__(16) float Fl[NPT * 36];
    __shared__ float Lw[NPT * 17];
    __shared__ int   Lb[NPT];
    __shared__ __align__(16) float Pk[256];
    __shared__ float W1kd[64], W1vd[64], zsl[32];
    int t = threadIdx.x;
    if (t < 64) { W1kd[t] = W1_kd[t]; W1vd[t] = W1_vd[t]; }
    Pk[t] = ws[WS_PK + t];
    if (t < 32) zsl[t] = 0.f;

    int li = t >> 3, g = t & 7;
    int n0 = blockIdx.x * NPT;
    int n = n0 + li;
    bool valid = n < NN;
    float4 fv4 = make_float4(0.f, 0.f, 0.f, 0.f);
    int b = 0;
    if (valid) {
        b = batch[n];
        fv4 = ((const float4*)nf)[n * 8 + g];
        ((float4*)(Fl + li * 36))[g] = fv4;
        if (g == 0) Lb[li] = b;
    } else {
        if (g == 0) Lb[li] = -1;
    }
    __syncthreads();

    if (valid) {
        float z = pos[3 * n + 2];
        float zminb = ws[WS_ZMIN + b];
        float zmaxb = ws[WS_ZMAX + b];
        float edge[2][8];
        bessel_edges(bw[0], z - zminb + DIST_C, zmaxb + DIST_C - z, edge);

        float up[8];
        const float4* Pk4 = (const float4*)Pk;
#pragma unroll
        for (int h = 0; h < 8; ++h) {
            float4 p = Pk4[h * 8 + g];
            up[h] = fv4.x * p.x + fv4.y * p.y + fv4.z * p.z + fv4.w * p.w;
        }
        float kd0, kd1;
        {
            float p0 = 0.f, p1 = 0.f;
#pragma unroll
            for (int k = 0; k < 8; ++k) {
                float w = W1kd[k * 8 + g];
                p0 += edge[0][k] * w;
                p1 += edge[1][k] * w;
            }
            kd0 = silu(p0); kd1 = silu(p1);
        }
        int lanebase = (t & 63) & 56;
        float sp0 = 0.f, sp1 = 0.f;
#pragma unroll
        for (int h = 0; h < 8; ++h) {
            sp0 += __shfl(kd0, lanebase + h, 64) * up[h];
            sp1 += __shfl(kd1, lanebase + h, 64) * up[h];
        }
#pragma unroll
        for (int m = 1; m < 8; m <<= 1) {
            sp0 += __shfl_xor(sp0, m, 64);
            sp1 += __shfl_xor(sp1, m, 64);
        }
        float ev0 = expf(sp0 * SCALE_C);
        float ev1 = expf(sp1 * SCALE_C);
        if (g == 0) {
            atomicAdd(&zsl[b * 2 + 0], ev0);
            atomicAdd(&zsl[b * 2 + 1], ev1);
        }
        float q0 = 0.f, q1 = 0.f;
#pragma unroll
        for (int k = 0; k < 8; ++k) {
            float w = W1vd[k * 8 + g];
            q0 += edge[0][k] * w;
            q1 += edge[1][k] * w;
        }
        Lw[li * 17 + g]     = ev0 * silu(q0);
        Lw[li * 17 + 8 + g] = ev1 * silu(q1);
    }
    __syncthreads();
    if (t < 32 && zsl[t] != 0.f) atomicAdd(&ws[WS_ZSUM + t], zsl[t]);

    // segment outer-product reduce: T[b][sh][d] += Lw[i][sh] * Fl[i][d]
    int count = NN - n0; if (count > NPT) count = NPT;
    int bf = Lb[0], bl = Lb[count - 1];
    int sh = t & 15, dp = t >> 4;
    for (int b2 = bf; b2 <= bl; ++b2) {
        float a0 = 0.f, a1 = 0.f;
        for (int i = 0; i < count; ++i) {
            if (Lb[i] != b2) continue;
            float w = Lw[i * 17 + sh];
            float2 x = *(const float2*)(Fl + i * 36 + 2 * dp);
            a0 += w * x.x;
            a1 += w * x.y;
        }
        float* Tb = ws + WS_T + b2 * 512 + sh * 32 + 2 * dp;
        atomicAdd(&Tb[0], a0);
        atomicAdd(&Tb[1], a1);
    }
}

// ---------------------------------------------------------------- K3: batch (once per (b,s))
__global__ __launch_bounds__(256) void k_batch(const float* __restrict__ init_dummy,
                                               const float* __restrict__ W2_vd,
                                               const float* __restrict__ W2_kg,
                                               const float* __restrict__ W2_vg,
                                               float* __restrict__ ws) {
    int bs = blockIdx.x;
    int b = bs >> 1, s = bs & 1;
    int t = threadIdx.x;
    __shared__ float Tl[256];
    __shared__ float part[256];
    __shared__ float dn[32];
    Tl[t] = ws[WS_T + b * 512 + s * 256 + t];
    __syncthreads();
    {   // part[h*32+e] = sum_d Tl[h*32+d] * W2_vd[h,d*32+e]
        int h = t >> 5, e = t & 31;
        float acc = 0.f;
#pragma unroll
        for (int d = 0; d < 32; ++d) acc += Tl[h * 32 + d] * W2_vd[h * 1024 + d * 32 + e];
        part[t] = acc;
    }
    __syncthreads();
    if (t < 32) {
        float acc = 0.f;
#pragma unroll
        for (int h = 0; h < 8; ++h) acc += part[h * 32 + t];
        float zs = ws[WS_ZSUM + b * 2 + s];
        dn[t] = init_dummy[t] + acc / zs;
    }
    __syncthreads();
    {
        int h = t >> 5, e = t & 31;
        float ak = 0.f, av = 0.f;
#pragma unroll
        for (int d = 0; d < 32; ++d) {
            float dv = dn[d];
            ak += dv * W2_kg[h * 1024 + d * 32 + e];
            av += dv * W2_vg[h * 1024 + d * 32 + e];
        }
        ws[WS_AKG + b * 512 + s * 256 + t] = ak;
        ws[WS_AVG + b * 512 + s * 256 + t] = av;
    }
}

// ---------------------------------------------------------------- K4: final
// 256 threads, 32 nodes/block. Stages precomputed AK/AV (<=2 batch slots, 8KB)
// into LDS; no B-phase recomputation.
__global__ __launch_bounds__(256) void k_fin(const float* __restrict__ pos,
                                             const int* __restrict__ batch,
                                             const float* __restrict__ nf,
                                             const float* __restrict__ bw,
                                             const float* __restrict__ W1_kg,
                                             const float* __restrict__ W1_vg,
                                             const float* __restrict__ ws,
                                             float* __restrict__ out) {
    __shared__ __align__(16) float Wc[1024];
    __shared__ __align__(16) float Fl[NPT * 36];
    __shared__ int   Lb[NPT];
    __shared__ float W1kg[64], W1vg[64];
    __shared__ __align__(16) float AK[2][512], AV[2][512];

    int t = threadIdx.x;
    int li = t >> 3, g = t & 7;
    int lanebase = (t & 63) & 56;
    {
        const float4* Wg4 = (const float4*)(ws + WS_WC);
        ((float4*)Wc)[t] = Wg4[t];
    }
    if (t < 64) { W1kg[t] = W1_kg[t]; W1vg[t] = W1_vg[t]; }

    int n0 = blockIdx.x * NPT;
    int n = n0 + li;
    int count = NN - n0; if (count > NPT) count = NPT;
    bool valid = li < count;
    float4 fv4 = make_float4(0.f, 0.f, 0.f, 0.f);
    float z = 0.f;
    int b = 0;
    if (valid) {
        b = batch[n];
        fv4 = ((const float4*)nf)[n * 8 + g];
        ((float4*)(Fl + li * 36))[g] = fv4;
        z = pos[3 * n + 2];
        if (g == 0) Lb[li] = b;
    }
    __syncthreads();
    int bf = Lb[0], bl = Lb[count - 1];
    int nseg = (bl != bf) ? 2 : 1;

    // stage AK/AV (float4: 512 f = 128 float4 per slot/array; 256 threads)
    for (int sl = 0; sl < nseg; ++sl) {
        int bb = sl ? bl : bf;
        const float4* Ag = (const float4*)(ws + WS_AKG + bb * 512);
        const float4* Vg = (const float4*)(ws + WS_AVG + bb * 512);
        if (t < 128) ((float4*)AK[sl])[t] = Ag[t];
        else         ((float4*)AV[sl])[t - 128] = Vg[t - 128];
    }
    __syncthreads();

    if (!valid) return;
    int slot = (b == bf) ? 0 : 1;
    const float4* Ak4 = (const float4*)AK[slot];
    const float4* Av4 = (const float4*)AV[slot];
    const float4* Wc4 = (const float4*)Wc;

    float zminb = ws[WS_ZMIN + b];
    float zmaxb = ws[WS_ZMAX + b];
    float edge[2][8];
    bessel_edges(bw[0], z - zminb + DIST_C, zmaxb + DIST_C - z, edge);

    float sk0, sk1, sv0, sv1;
    {
        float pk0 = 0.f, pk1 = 0.f, pv0 = 0.f, pv1 = 0.f;
#pragma unroll
        for (int k = 0; k < 8; ++k) {
            float wk = W1kg[k * 8 + g];
            float wv = W1vg[k * 8 + g];
            pk0 += edge[0][k] * wk; pk1 += edge[1][k] * wk;
            pv0 += edge[0][k] * wv; pv1 += edge[1][k] * wv;
        }
        sk0 = silu(pk0); sk1 = silu(pk1);
        sv0 = silu(pv0); sv1 = silu(pv1);
    }
    float4 q4 = make_float4(0.f, 0.f, 0.f, 0.f);
    const float* myF = Fl + li * 36;
#pragma unroll
    for (int d = 0; d < 32; ++d) {
        float fd = myF[d];
        float4 w = Wc4[d * 8 + g];
        q4.x += fd * w.x; q4.y += fd * w.y; q4.z += fd * w.z; q4.w += fd * w.w;
    }
    float p0 = 0.f, p1 = 0.f;
#pragma unroll
    for (int h = 0; h < 8; ++h) {
        float4 a0 = Ak4[h * 8 + g];
        float4 a1 = Ak4[64 + h * 8 + g];
        float d0 = q4.x * a0.x + q4.y * a0.y + q4.z * a0.z + q4.w * a0.w;
        float d1 = q4.x * a1.x + q4.y * a1.y + q4.z * a1.z + q4.w * a1.w;
        p0 += __shfl(sk0, lanebase + h, 64) * d0;
        p1 += __shfl(sk1, lanebase + h, 64) * d1;
    }
#pragma unroll
    for (int m = 1; m < 8; m <<= 1) {
        p0 += __shfl_xor(p0, m, 64);
        p1 += __shfl_xor(p1, m, 64);
    }
    float sg0 = p0 * SCALE_C, sg1 = p1 * SCALE_C;
    float mx = fmaxf(sg0, sg1);
    float e0 = expf(sg0 - mx), e1 = expf(sg1 - mx);
    float inv = 1.0f / (e0 + e1);
    float ag0 = e0 * inv, ag1 = e1 * inv;

    float4 x4 = fv4;
#pragma unroll
    for (int h = 0; h < 8; ++h) {
        float w0 = ag0 * __shfl(sv0, lanebase + h, 64);
        float w1 = ag1 * __shfl(sv1, lanebase + h, 64);
        float4 a0 = Av4[h * 8 + g];
        float4 a1 = Av4[64 + h * 8 + g];
        x4.x += w0 * a0.x + w1 * a1.x;
        x4.y += w0 * a0.y + w1 * a1.y;
        x4.z += w0 * a0.z + w1 * a1.z;
        x4.w += w0 * a0.w + w1 * a1.w;
    }
    ((float4*)out)[n * 8 + g] = x4;
}

extern "C" void kernel_launch(void* const* d_in, const int* in_sizes, int n_in,
                              void* d_out, int out_size, void* d_ws, size_t ws_size,
                              hipStream_t stream) {
    const float* pos        = (const float*)d_in[0];
    const float* nf         = (const float*)d_in[1];
    const int*   batch      = (const int*)d_in[2];
    const float* bw         = (const float*)d_in[3];
    const float* init_dummy = (const float*)d_in[4];
    const float* Wq_dummy   = (const float*)d_in[5];
    const float* Wq_graph   = (const float*)d_in[6];
    const float* Wdot       = (const float*)d_in[7];
    const float* W1_kd      = (const float*)d_in[8];
    const float* W2_kd      = (const float*)d_in[9];
    const float* W1_vd      = (const float*)d_in[10];
    const float* W2_vd      = (const float*)d_in[11];
    const float* W1_kg      = (const float*)d_in[12];
    const float* W2_kg      = (const float*)d_in[13];
    const float* W1_vg      = (const float*)d_in[14];
    const float* W2_vg      = (const float*)d_in[15];
    float* ws  = (float*)d_ws;
    float* out = (float*)d_out;

    int nblk = (NN + NPT - 1) / NPT;   // 938
    hipLaunchKernelGGL(k_pre, dim3(34), dim3(256), 0, stream,
                       pos, batch, init_dummy, Wq_dummy, Wdot, W2_kd, Wq_graph, ws);
    hipLaunchKernelGGL(k_phase1, dim3(nblk), dim3(256), 0, stream,
                       pos, batch, nf, bw, W1_kd, W1_vd, ws);
    hipLaunchKernelGGL(k_batch, dim3(32), dim3(256), 0, stream,
                       init_dummy, W2_vd, W2_kg, W2_vg, ws);
    hipLaunchKernelGGL(k_fin, dim3(nblk), dim3(256), 0, stream,
                       pos, batch, nf, bw, W1_kg, W1_vg, ws, out);
}

// Round 10
// 120.547 us; speedup vs baseline: 1.2823x; 1.0197x over previous
//
#include <hip/hip_runtime.h>
#include <math.h>

#define NN 30000
#define DIST_C 5.0f
#define EPS_C 1e-6f
#define SCALE_C 0.17677669529663687f  // 1/sqrt(32)

// workspace float offsets (total ~26K floats = 104 KB, verified-safe footprint)
#define WS_ZMIN 0      // 16 f (plain floats)
#define WS_ZMAX 16     // 16 f
#define WS_ZSUM 32     // 32 f  [b*2+s]
#define WS_T    64     // 8192 f [b*512 + (s*8+h)*32 + d]
#define WS_PK   8256   // 256 f [h*32+d]
#define WS_WC   8512   // 1024 f [d*32+e]
#define WS_AKG  9536   // 8192 f [b*512 + s*256 + h*32 + e]
#define WS_AVG  17728  // 8192 f

#define NPT 32         // nodes per tile (8 threads/node, 256-thread blocks)

__device__ __forceinline__ float silu(float x) { return x / (1.0f + __expf(-x)); }

// edge[s][k] = sin(bw_k*x_s)/(x_s+eps); bw_k=(k+1)*bw0. Chebyshev recurrence
// seeded by hardware __sincosf (|th| <= ~100 rad, well within reduction range;
// seed err ~1e-6, amplification <= ~2^7 -> ~1e-4 << 0.1 threshold).
__device__ __forceinline__ void bessel_edges(float bw0, float x0, float x1, float edge[2][8]) {
    float xs[2]; xs[0] = x0; xs[1] = x1;
#pragma unroll
    for (int s = 0; s < 2; ++s) {
        float x = xs[s];
        float inv = 1.0f / (x + EPS_C);
        float th = bw0 * x;
        float sk, ck;
        __sincosf(th, &sk, &ck);
        float c2 = 2.0f * ck;
        float skm1 = 0.0f;
#pragma unroll
        for (int k = 0; k < 8; ++k) {
            edge[s][k] = sk * inv;
            float nx = c2 * sk - skm1;
            skm1 = sk; sk = nx;
        }
    }
}

// ---------------------------------------------------------------- K1: pre
// blocks 0-15: per-batch zminmax; block 16: Pk chain; block 17: Wc;
// blocks 18-33: zero T + ZSUM.
__global__ __launch_bounds__(256) void k_pre(const float* __restrict__ pos,
                                             const int* __restrict__ batch,
                                             const float* __restrict__ init_dummy,
                                             const float* __restrict__ Wq_dummy,
                                             const float* __restrict__ Wdot,
                                             const float* __restrict__ W2_kd,
                                             const float* __restrict__ Wq_graph,
                                             float* __restrict__ ws) {
    int t = threadIdx.x, blk = blockIdx.x;
    if (blk < 16) {
        __shared__ int bnd2[2];
        __shared__ float r[8];
        if (t < 2) {
            int target = blk + t;
            int lo = 0, hi = NN;
            while (lo < hi) { int mid = (lo + hi) >> 1; if (batch[mid] < target) lo = mid + 1; else hi = mid; }
            bnd2[t] = lo;
        }
        __syncthreads();
        int s0 = bnd2[0], s1 = bnd2[1];
        float zmn = 3.4e38f, zmx = -3.4e38f;
        for (int i = s0 + t; i < s1; i += 256) {
            float v = pos[3 * i + 2];
            zmn = fminf(zmn, v); zmx = fmaxf(zmx, v);
        }
#pragma unroll
        for (int off = 1; off < 64; off <<= 1) {
            zmn = fminf(zmn, __shfl_xor(zmn, off, 64));
            zmx = fmaxf(zmx, __shfl_xor(zmx, off, 64));
        }
        if ((t & 63) == 0) { r[(t >> 6) * 2] = zmn; r[(t >> 6) * 2 + 1] = zmx; }
        __syncthreads();
        if (t == 0) {
            ws[WS_ZMIN + blk] = fminf(fminf(r[0], r[2]), fminf(r[4], r[6]));
            ws[WS_ZMAX + blk] = fmaxf(fmaxf(r[1], r[3]), fmaxf(r[5], r[7]));
        }
    } else if (blk == 16) {
        __shared__ float qv[32], qW[32];
        if (t < 32) {
            float acc = 0.f;
            for (int d = 0; d < 32; ++d) acc += init_dummy[d] * Wq_dummy[d * 32 + t];
            qv[t] = acc;
        }
        __syncthreads();
        if (t < 32) {
            float acc = 0.f;
            for (int e = 0; e < 32; ++e) acc += qv[e] * Wdot[e * 32 + t];
            qW[t] = acc;
        }
        __syncthreads();
        int h = t >> 5, d = t & 31;
        float acc = 0.f;
        for (int e = 0; e < 32; ++e) acc += W2_kd[h * 1024 + d * 32 + e] * qW[e];
        ws[WS_PK + t] = acc;
    } else if (blk == 17) {
        for (int i = t; i < 1024; i += 256) {
            int d = i >> 5, e = i & 31;
            float acc = 0.f;
            for (int m = 0; m < 32; ++m) acc += Wq_graph[d * 32 + m] * Wdot[m * 32 + e];
            ws[WS_WC + i] = acc;
        }
    } else {
        int idx = blk - 18;
        ws[WS_T + idx * 512 + t] = 0.f;
        ws[WS_T + idx * 512 + 256 + t] = 0.f;
        if (idx == 0 && t < 32) ws[WS_ZSUM + t] = 0.f;
    }
}

// ---------------------------------------------------------------- K2: phase 1
// 256 threads, 32 nodes/block (8 threads per node): t = li*8 + g.
// Fl row stride 36 floats; Lw row stride 17.
__global__ __launch_bounds__(256) void k_phase1(const float* __restrict__ pos,
                                                const int* __restrict__ batch,
                                                const float* __restrict__ nf,
                                                const float* __restrict__ bw,
                                                const float* __restrict__ W1_kd,
                                                const float* __restrict__ W1_vd,
                                                float* __restrict__ ws) {
    __shared__ __align__(16) float Fl[NPT * 36];
    __shared__ float Lw[NPT * 17];
    __shared__ int   Lb[NPT];
    __shared__ __align__(16) float Pk[256];
    __shared__ float W1kd[64], W1vd[64], zsl[32];
    int t = threadIdx.x;
    if (t < 64) { W1kd[t] = W1_kd[t]; W1vd[t] = W1_vd[t]; }
    Pk[t] = ws[WS_PK + t];
    if (t < 32) zsl[t] = 0.f;

    int li = t >> 3, g = t & 7;
    int n0 = blockIdx.x * NPT;
    int n = n0 + li;
    bool valid = n < NN;
    float4 fv4 = make_float4(0.f, 0.f, 0.f, 0.f);
    int b = 0;
    if (valid) {
        b = batch[n];
        fv4 = ((const float4*)nf)[n * 8 + g];
        ((float4*)(Fl + li * 36))[g] = fv4;
        if (g == 0) Lb[li] = b;
    } else {
        if (g == 0) Lb[li] = -1;
    }
    __syncthreads();

    if (valid) {
        float z = pos[3 * n + 2];
        float zminb = ws[WS_ZMIN + b];
        float zmaxb = ws[WS_ZMAX + b];
        float edge[2][8];
        bessel_edges(bw[0], z - zminb + DIST_C, zmaxb + DIST_C - z, edge);

        float up[8];
        const float4* Pk4 = (const float4*)Pk;
#pragma unroll
        for (int h = 0; h < 8; ++h) {
            float4 p = Pk4[h * 8 + g];
            up[h] = fv4.x * p.x + fv4.y * p.y + fv4.z * p.z + fv4.w * p.w;
        }
        float kd0, kd1;
        {
            float p0 = 0.f, p1 = 0.f;
#pragma unroll
            for (int k = 0; k < 8; ++k) {
                float w = W1kd[k * 8 + g];
                p0 += edge[0][k] * w;
                p1 += edge[1][k] * w;
            }
            kd0 = silu(p0); kd1 = silu(p1);
        }
        int lanebase = (t & 63) & 56;
        float sp0 = 0.f, sp1 = 0.f;
#pragma unroll
        for (int h = 0; h < 8; ++h) {
            sp0 += __shfl(kd0, lanebase + h, 64) * up[h];
            sp1 += __shfl(kd1, lanebase + h, 64) * up[h];
        }
#pragma unroll
        for (int m = 1; m < 8; m <<= 1) {
            sp0 += __shfl_xor(sp0, m, 64);
            sp1 += __shfl_xor(sp1, m, 64);
        }
        float ev0 = __expf(sp0 * SCALE_C);
        float ev1 = __expf(sp1 * SCALE_C);
        if (g == 0) {
            atomicAdd(&zsl[b * 2 + 0], ev0);
            atomicAdd(&zsl[b * 2 + 1], ev1);
        }
        float q0 = 0.f, q1 = 0.f;
#pragma unroll
        for (int k = 0; k < 8; ++k) {
            float w = W1vd[k * 8 + g];
            q0 += edge[0][k] * w;
            q1 += edge[1][k] * w;
        }
        Lw[li * 17 + g]     = ev0 * silu(q0);
        Lw[li * 17 + 8 + g] = ev1 * silu(q1);
    }
    __syncthreads();
    if (t < 32 && zsl[t] != 0.f) atomicAdd(&ws[WS_ZSUM + t], zsl[t]);

    // segment outer-product reduce: T[b][sh][d] += Lw[i][sh] * Fl[i][d]
    int count = NN - n0; if (count > NPT) count = NPT;
    int bf = Lb[0], bl = Lb[count - 1];
    int sh = t & 15, dp = t >> 4;
    for (int b2 = bf; b2 <= bl; ++b2) {
        float a0 = 0.f, a1 = 0.f;
        for (int i = 0; i < count; ++i) {
            if (Lb[i] != b2) continue;
            float w = Lw[i * 17 + sh];
            float2 x = *(const float2*)(Fl + i * 36 + 2 * dp);
            a0 += w * x.x;
            a1 += w * x.y;
        }
        float* Tb = ws + WS_T + b2 * 512 + sh * 32 + 2 * dp;
        atomicAdd(&Tb[0], a0);
        atomicAdd(&Tb[1], a1);
    }
}

// ---------------------------------------------------------------- K3: batch (once per (b,s))
__global__ __launch_bounds__(256) void k_batch(const float* __restrict__ init_dummy,
                                               const float* __restrict__ W2_vd,
                                               const float* __restrict__ W2_kg,
                                               const float* __restrict__ W2_vg,
                                               float* __restrict__ ws) {
    int bs = blockIdx.x;
    int b = bs >> 1, s = bs & 1;
    int t = threadIdx.x;
    __shared__ float Tl[256];
    __shared__ float part[256];
    __shared__ float dn[32];
    Tl[t] = ws[WS_T + b * 512 + s * 256 + t];
    __syncthreads();
    {   // part[h*32+e] = sum_d Tl[h*32+d] * W2_vd[h,d*32+e]
        int h = t >> 5, e = t & 31;
        float acc = 0.f;
#pragma unroll
        for (int d = 0; d < 32; ++d) acc += Tl[h * 32 + d] * W2_vd[h * 1024 + d * 32 + e];
        part[t] = acc;
    }
    __syncthreads();
    if (t < 32) {
        float acc = 0.f;
#pragma unroll
        for (int h = 0; h < 8; ++h) acc += part[h * 32 + t];
        float zs = ws[WS_ZSUM + b * 2 + s];
        dn[t] = init_dummy[t] + acc / zs;
    }
    __syncthreads();
    {
        int h = t >> 5, e = t & 31;
        float ak = 0.f, av = 0.f;
#pragma unroll
        for (int d = 0; d < 32; ++d) {
            float dv = dn[d];
            ak += dv * W2_kg[h * 1024 + d * 32 + e];
            av += dv * W2_vg[h * 1024 + d * 32 + e];
        }
        ws[WS_AKG + b * 512 + s * 256 + t] = ak;
        ws[WS_AVG + b * 512 + s * 256 + t] = av;
    }
}

// ---------------------------------------------------------------- K4: final
// 256 threads, 32 nodes/block. Stages precomputed AK/AV (<=2 batch slots, 8KB)
// into LDS; no B-phase recomputation.
__global__ __launch_bounds__(256) void k_fin(const float* __restrict__ pos,
                                             const int* __restrict__ batch,
                                             const float* __restrict__ nf,
                                             const float* __restrict__ bw,
                                             const float* __restrict__ W1_kg,
                                             const float* __restrict__ W1_vg,
                                             const float* __restrict__ ws,
                                             float* __restrict__ out) {
    __shared__ __align__(16) float Wc[1024];
    __shared__ __align__(16) float Fl[NPT * 36];
    __shared__ int   Lb[NPT];
    __shared__ float W1kg[64], W1vg[64];
    __shared__ __align__(16) float AK[2][512], AV[2][512];

    int t = threadIdx.x;
    int li = t >> 3, g = t & 7;
    int lanebase = (t & 63) & 56;
    {
        const float4* Wg4 = (const float4*)(ws + WS_WC);
        ((float4*)Wc)[t] = Wg4[t];
    }
    if (t < 64) { W1kg[t] = W1_kg[t]; W1vg[t] = W1_vg[t]; }

    int n0 = blockIdx.x * NPT;
    int n = n0 + li;
    int count = NN - n0; if (count > NPT) count = NPT;
    bool valid = li < count;
    float4 fv4 = make_float4(0.f, 0.f, 0.f, 0.f);
    float z = 0.f;
    int b = 0;
    if (valid) {
        b = batch[n];
        fv4 = ((const float4*)nf)[n * 8 + g];
        ((float4*)(Fl + li * 36))[g] = fv4;
        z = pos[3 * n + 2];
        if (g == 0) Lb[li] = b;
    }
    __syncthreads();
    int bf = Lb[0], bl = Lb[count - 1];
    int nseg = (bl != bf) ? 2 : 1;

    // stage AK/AV (float4: 512 f = 128 float4 per slot/array; 256 threads)
    for (int sl = 0; sl < nseg; ++sl) {
        int bb = sl ? bl : bf;
        const float4* Ag = (const float4*)(ws + WS_AKG + bb * 512);
        const float4* Vg = (const float4*)(ws + WS_AVG + bb * 512);
        if (t < 128) ((float4*)AK[sl])[t] = Ag[t];
        else         ((float4*)AV[sl])[t - 128] = Vg[t - 128];
    }
    __syncthreads();

    if (!valid) return;
    int slot = (b == bf) ? 0 : 1;
    const float4* Ak4 = (const float4*)AK[slot];
    const float4* Av4 = (const float4*)AV[slot];
    const float4* Wc4 = (const float4*)Wc;

    float zminb = ws[WS_ZMIN + b];
    float zmaxb = ws[WS_ZMAX + b];
    float edge[2][8];
    bessel_edges(bw[0], z - zminb + DIST_C, zmaxb + DIST_C - z, edge);

    float sk0, sk1, sv0, sv1;
    {
        float pk0 = 0.f, pk1 = 0.f, pv0 = 0.f, pv1 = 0.f;
#pragma unroll
        for (int k = 0; k < 8; ++k) {
            float wk = W1kg[k * 8 + g];
            float wv = W1vg[k * 8 + g];
            pk0 += edge[0][k] * wk; pk1 += edge[1][k] * wk;
            pv0 += edge[0][k] * wv; pv1 += edge[1][k] * wv;
        }
        sk0 = silu(pk0); sk1 = silu(pk1);
        sv0 = silu(pv0); sv1 = silu(pv1);
    }
    float4 q4 = make_float4(0.f, 0.f, 0.f, 0.f);
    const float* myF = Fl + li * 36;
#pragma unroll
    for (int d = 0; d < 32; ++d) {
        float fd = myF[d];
        float4 w = Wc4[d * 8 + g];
        q4.x += fd * w.x; q4.y += fd * w.y; q4.z += fd * w.z; q4.w += fd * w.w;
    }
    float p0 = 0.f, p1 = 0.f;
#pragma unroll
    for (int h = 0; h < 8; ++h) {
        float4 a0 = Ak4[h * 8 + g];
        float4 a1 = Ak4[64 + h * 8 + g];
        float d0 = q4.x * a0.x + q4.y * a0.y + q4.z * a0.z + q4.w * a0.w;
        float d1 = q4.x * a1.x + q4.y * a1.y + q4.z * a1.z + q4.w * a1.w;
        p0 += __shfl(sk0, lanebase + h, 64) * d0;
        p1 += __shfl(sk1, lanebase + h, 64) * d1;
    }
#pragma unroll
    for (int m = 1; m < 8; m <<= 1) {
        p0 += __shfl_xor(p0, m, 64);
        p1 += __shfl_xor(p1, m, 64);
    }
    float sg0 = p0 * SCALE_C, sg1 = p1 * SCALE_C;
    float mx = fmaxf(sg0, sg1);
    float e0 = __expf(sg0 - mx), e1 = __expf(sg1 - mx);
    float inv = 1.0f / (e0 + e1);
    float ag0 = e0 * inv, ag1 = e1 * inv;

    float4 x4 = fv4;
#pragma unroll
    for (int h = 0; h < 8; ++h) {
        float w0 = ag0 * __shfl(sv0, lanebase + h, 64);
        float w1 = ag1 * __shfl(sv1, lanebase + h, 64);
        float4 a0 = Av4[h * 8 + g];
        float4 a1 = Av4[64 + h * 8 + g];
        x4.x += w0 * a0.x + w1 * a1.x;
        x4.y += w0 * a0.y + w1 * a1.y;
        x4.z += w0 * a0.z + w1 * a1.z;
        x4.w += w0 * a0.w + w1 * a1.w;
    }
    ((float4*)out)[n * 8 + g] = x4;
}

extern "C" void kernel_launch(void* const* d_in, const int* in_sizes, int n_in,
                              void* d_out, int out_size, void* d_ws, size_t ws_size,
                              hipStream_t stream) {
    const float* pos        = (const float*)d_in[0];
    const float* nf         = (const float*)d_in[1];
    const int*   batch      = (const int*)d_in[2];
    const float* bw         = (const float*)d_in[3];
    const float* init_dummy = (const float*)d_in[4];
    const float* Wq_dummy   = (const float*)d_in[5];
    const float* Wq_graph   = (const float*)d_in[6];
    const float* Wdot       = (const float*)d_in[7];
    const float* W1_kd      = (const float*)d_in[8];
    const float* W2_kd      = (const float*)d_in[9];
    const float* W1_vd      = (const float*)d_in[10];
    const float* W2_vd      = (const float*)d_in[11];
    const float* W1_kg      = (const float*)d_in[12];
    const float* W2_kg      = (const float*)d_in[13];
    const float* W1_vg      = (const float*)d_in[14];
    const float* W2_vg      = (const float*)d_in[15];
    float* ws  = (float*)d_ws;
    float* out = (float*)d_out;

    int nblk = (NN + NPT - 1) / NPT;   // 938
    hipLaunchKernelGGL(k_pre, dim3(34), dim3(256), 0, stream,
                       pos, batch, init_dummy, Wq_dummy, Wdot, W2_kd, Wq_graph, ws);
    hipLaunchKernelGGL(k_phase1, dim3(nblk), dim3(256), 0, stream,
                       pos, batch, nf, bw, W1_kd, W1_vd, ws);
    hipLaunchKernelGGL(k_batch, dim3(32), dim3(256), 0, stream,
                       init_dummy, W2_vd, W2_kg, W2_vg, ws);
    hipLaunchKernelGGL(k_fin, dim3(nblk), dim3(256), 0, stream,
                       pos, batch, nf, bw, W1_kg, W1_vg, ws, out);
}

// Round 11
// 117.958 us; speedup vs baseline: 1.3104x; 1.0220x over previous
//
#include <hip/hip_runtime.h>
#include <math.h>

#define NN 30000
#define DIST_C 5.0f
#define EPS_C 1e-6f
#define SCALE_C 0.17677669529663687f  // 1/sqrt(32)

// workspace float offsets (total ~26K floats = 104 KB)
#define WS_ZMIN 0      // 16 f (plain floats)
#define WS_ZMAX 16     // 16 f
#define WS_ZSUM 32     // 32 f  [b*2+s]
#define WS_T    64     // 8192 f [b*512 + (s*8+h)*32 + d]
#define WS_PK   8256   // 256 f [h*32+d]
#define WS_WC   8512   // 1024 f [d*32+e]
#define WS_AKG  9536   // 8192 f [b*512 + s*256 + h*32 + e]
#define WS_AVG  17728  // 8192 f

#define NPT 32         // nodes per tile (8 threads/node, 256-thread blocks)

__device__ __forceinline__ float silu(float x) { return x / (1.0f + __expf(-x)); }

// edge[s][k] = sin(bw_k*x_s)/(x_s+eps); bw_k=(k+1)*bw0. Chebyshev recurrence
// seeded by hardware __sincosf (seed err ~1e-6, amplification <= ~2^7 -> ~1e-4
// << 0.1 threshold).
__device__ __forceinline__ void bessel_edges(float bw0, float x0, float x1, float edge[2][8]) {
    float xs[2]; xs[0] = x0; xs[1] = x1;
#pragma unroll
    for (int s = 0; s < 2; ++s) {
        float x = xs[s];
        float inv = 1.0f / (x + EPS_C);
        float th = bw0 * x;
        float sk, ck;
        __sincosf(th, &sk, &ck);
        float c2 = 2.0f * ck;
        float skm1 = 0.0f;
#pragma unroll
        for (int k = 0; k < 8; ++k) {
            edge[s][k] = sk * inv;
            float nx = c2 * sk - skm1;
            skm1 = sk; sk = nx;
        }
    }
}

// ---------------------------------------------------------------- K1: pre
// blocks 0-15: per-batch zminmax; block 16: Pk chain; block 17: Wc;
// blocks 18-33: zero T + ZSUM.
__global__ __launch_bounds__(256) void k_pre(const float* __restrict__ pos,
                                             const int* __restrict__ batch,
                                             const float* __restrict__ init_dummy,
                                             const float* __restrict__ Wq_dummy,
                                             const float* __restrict__ Wdot,
                                             const float* __restrict__ W2_kd,
                                             const float* __restrict__ Wq_graph,
                                             float* __restrict__ ws) {
    int t = threadIdx.x, blk = blockIdx.x;
    if (blk < 16) {
        __shared__ int bnd2[2];
        __shared__ float r[8];
        if (t < 2) {
            int target = blk + t;
            int lo = 0, hi = NN;
            while (lo < hi) { int mid = (lo + hi) >> 1; if (batch[mid] < target) lo = mid + 1; else hi = mid; }
            bnd2[t] = lo;
        }
        __syncthreads();
        int s0 = bnd2[0], s1 = bnd2[1];
        float zmn = 3.4e38f, zmx = -3.4e38f;
        for (int i = s0 + t; i < s1; i += 256) {
            float v = pos[3 * i + 2];
            zmn = fminf(zmn, v); zmx = fmaxf(zmx, v);
        }
#pragma unroll
        for (int off = 1; off < 64; off <<= 1) {
            zmn = fminf(zmn, __shfl_xor(zmn, off, 64));
            zmx = fmaxf(zmx, __shfl_xor(zmx, off, 64));
        }
        if ((t & 63) == 0) { r[(t >> 6) * 2] = zmn; r[(t >> 6) * 2 + 1] = zmx; }
        __syncthreads();
        if (t == 0) {
            ws[WS_ZMIN + blk] = fminf(fminf(r[0], r[2]), fminf(r[4], r[6]));
            ws[WS_ZMAX + blk] = fmaxf(fmaxf(r[1], r[3]), fmaxf(r[5], r[7]));
        }
    } else if (blk == 16) {
        __shared__ float qv[32], qW[32];
        if (t < 32) {
            float acc = 0.f;
            for (int d = 0; d < 32; ++d) acc += init_dummy[d] * Wq_dummy[d * 32 + t];
            qv[t] = acc;
        }
        __syncthreads();
        if (t < 32) {
            float acc = 0.f;
            for (int e = 0; e < 32; ++e) acc += qv[e] * Wdot[e * 32 + t];
            qW[t] = acc;
        }
        __syncthreads();
        int h = t >> 5, d = t & 31;
        float acc = 0.f;
        for (int e = 0; e < 32; ++e) acc += W2_kd[h * 1024 + d * 32 + e] * qW[e];
        ws[WS_PK + t] = acc;
    } else if (blk == 17) {
        for (int i = t; i < 1024; i += 256) {
            int d = i >> 5, e = i & 31;
            float acc = 0.f;
            for (int m = 0; m < 32; ++m) acc += Wq_graph[d * 32 + m] * Wdot[m * 32 + e];
            ws[WS_WC + i] = acc;
        }
    } else {
        int idx = blk - 18;
        ws[WS_T + idx * 512 + t] = 0.f;
        ws[WS_T + idx * 512 + 256 + t] = 0.f;
        if (idx == 0 && t < 32) ws[WS_ZSUM + t] = 0.f;
    }
}

// ---------------------------------------------------------------- K2: phase 1
// 256 threads, 32 nodes/block (8 threads per node): t = li*8 + g.
// Fl row stride 36 floats; Lw row stride 17. Branch-free segment reduce via
// __syncthreads_count (batch sorted -> first-segment prefix length nbf).
__global__ __launch_bounds__(256) void k_phase1(const float* __restrict__ pos,
                                                const int* __restrict__ batch,
                                                const float* __restrict__ nf,
                                                const float* __restrict__ bw,
                                                const float* __restrict__ W1_kd,
                                                const float* __restrict__ W1_vd,
                                                float* __restrict__ ws) {
    __shared__ __align__(16) float Fl[NPT * 36];
    __shared__ float Lw[NPT * 17];
    __shared__ int   Lb[NPT];
    __shared__ __align__(16) float Pk[256];
    __shared__ float W1kd[64], W1vd[64], zsl[32];
    int t = threadIdx.x;
    if (t < 64) { W1kd[t] = W1_kd[t]; W1vd[t] = W1_vd[t]; }
    Pk[t] = ws[WS_PK + t];
    if (t < 32) zsl[t] = 0.f;

    int li = t >> 3, g = t & 7;
    int n0 = blockIdx.x * NPT;
    int n = n0 + li;
    int count = NN - n0; if (count > NPT) count = NPT;
    bool valid = li < count;
    float4 fv4 = make_float4(0.f, 0.f, 0.f, 0.f);
    float z = 0.f;
    int b = 0;
    if (valid) {
        b = batch[n];
        fv4 = ((const float4*)nf)[n * 8 + g];
        ((float4*)(Fl + li * 36))[g] = fv4;
        z = pos[3 * n + 2];
        if (g == 0) Lb[li] = b;
    }
    __syncthreads();
    int bf = Lb[0], bl = Lb[count - 1];

    if (valid) {
        float zminb = ws[WS_ZMIN + b];
        float zmaxb = ws[WS_ZMAX + b];
        float edge[2][8];
        bessel_edges(bw[0], z - zminb + DIST_C, zmaxb + DIST_C - z, edge);

        float up[8];
        const float4* Pk4 = (const float4*)Pk;
#pragma unroll
        for (int h = 0; h < 8; ++h) {
            float4 p = Pk4[h * 8 + g];
            up[h] = fv4.x * p.x + fv4.y * p.y + fv4.z * p.z + fv4.w * p.w;
        }
        float kd0, kd1;
        {
            float p0 = 0.f, p1 = 0.f;
#pragma unroll
            for (int k = 0; k < 8; ++k) {
                float w = W1kd[k * 8 + g];
                p0 += edge[0][k] * w;
                p1 += edge[1][k] * w;
            }
            kd0 = silu(p0); kd1 = silu(p1);
        }
        int lanebase = (t & 63) & 56;
        float sp0 = 0.f, sp1 = 0.f;
#pragma unroll
        for (int h = 0; h < 8; ++h) {
            sp0 += __shfl(kd0, lanebase + h, 64) * up[h];
            sp1 += __shfl(kd1, lanebase + h, 64) * up[h];
        }
#pragma unroll
        for (int m = 1; m < 8; m <<= 1) {
            sp0 += __shfl_xor(sp0, m, 64);
            sp1 += __shfl_xor(sp1, m, 64);
        }
        float ev0 = __expf(sp0 * SCALE_C);
        float ev1 = __expf(sp1 * SCALE_C);
        if (g == 0) {
            atomicAdd(&zsl[b * 2 + 0], ev0);
            atomicAdd(&zsl[b * 2 + 1], ev1);
        }
        float q0 = 0.f, q1 = 0.f;
#pragma unroll
        for (int k = 0; k < 8; ++k) {
            float w = W1vd[k * 8 + g];
            q0 += edge[0][k] * w;
            q1 += edge[1][k] * w;
        }
        Lw[li * 17 + g]     = ev0 * silu(q0);
        Lw[li * 17 + 8 + g] = ev1 * silu(q1);
    }
    // barrier + first-segment node count (batch sorted -> prefix property)
    int nbf = __syncthreads_count(g == 0 && valid && b == bf);
    if (t < 32 && zsl[t] != 0.f) atomicAdd(&ws[WS_ZSUM + t], zsl[t]);

    // branch-free segment outer-product reduce:
    // thread owns (sh = t&15, dims 2*dp, 2*dp+1); loop [0,nbf) -> bf,
    // [nbf,count) -> bl (only straddling blocks, ~15/938).
    int sh = t & 15, dp = t >> 4;
    {
        float a0 = 0.f, a1 = 0.f;
        for (int i = 0; i < nbf; ++i) {
            float w = Lw[i * 17 + sh];
            float2 x = *(const float2*)(Fl + i * 36 + 2 * dp);
            a0 += w * x.x;
            a1 += w * x.y;
        }
        float* Tb = ws + WS_T + bf * 512 + sh * 32 + 2 * dp;
        atomicAdd(&Tb[0], a0);
        atomicAdd(&Tb[1], a1);
    }
    if (nbf < count) {
        float a0 = 0.f, a1 = 0.f;
        for (int i = nbf; i < count; ++i) {
            float w = Lw[i * 17 + sh];
            float2 x = *(const float2*)(Fl + i * 36 + 2 * dp);
            a0 += w * x.x;
            a1 += w * x.y;
        }
        float* Tb = ws + WS_T + bl * 512 + sh * 32 + 2 * dp;
        atomicAdd(&Tb[0], a0);
        atomicAdd(&Tb[1], a1);
    }
}

// ---------------------------------------------------------------- K3: batch (once per (b,s))
__global__ __launch_bounds__(256) void k_batch(const float* __restrict__ init_dummy,
                                               const float* __restrict__ W2_vd,
                                               const float* __restrict__ W2_kg,
                                               const float* __restrict__ W2_vg,
                                               float* __restrict__ ws) {
    int bs = blockIdx.x;
    int b = bs >> 1, s = bs & 1;
    int t = threadIdx.x;
    __shared__ float Tl[256];
    __shared__ float part[256];
    __shared__ float dn[32];
    Tl[t] = ws[WS_T + b * 512 + s * 256 + t];
    __syncthreads();
    {   // part[h*32+e] = sum_d Tl[h*32+d] * W2_vd[h,d*32+e]
        int h = t >> 5, e = t & 31;
        float acc = 0.f;
#pragma unroll
        for (int d = 0; d < 32; ++d) acc += Tl[h * 32 + d] * W2_vd[h * 1024 + d * 32 + e];
        part[t] = acc;
    }
    __syncthreads();
    if (t < 32) {
        float acc = 0.f;
#pragma unroll
        for (int h = 0; h < 8; ++h) acc += part[h * 32 + t];
        float zs = ws[WS_ZSUM + b * 2 + s];
        dn[t] = init_dummy[t] + acc / zs;
    }
    __syncthreads();
    {
        int h = t >> 5, e = t & 31;
        float ak = 0.f, av = 0.f;
#pragma unroll
        for (int d = 0; d < 32; ++d) {
            float dv = dn[d];
            ak += dv * W2_kg[h * 1024 + d * 32 + e];
            av += dv * W2_vg[h * 1024 + d * 32 + e];
        }
        ws[WS_AKG + b * 512 + s * 256 + t] = ak;
        ws[WS_AVG + b * 512 + s * 256 + t] = av;
    }
}

// ---------------------------------------------------------------- K4: final
// 256 threads, 32 nodes/block. Stages precomputed AK/AV (<=2 batch slots, 8KB)
// into LDS; no B-phase recomputation.
__global__ __launch_bounds__(256) void k_fin(const float* __restrict__ pos,
                                             const int* __restrict__ batch,
                                             const float* __restrict__ nf,
                                             const float* __restrict__ bw,
                                             const float* __restrict__ W1_kg,
                                             const float* __restrict__ W1_vg,
                                             const float* __restrict__ ws,
                                             float* __restrict__ out) {
    __shared__ __align__(16) float Wc[1024];
    __shared__ __align__(16) float Fl[NPT * 36];
    __shared__ int   Lb[NPT];
    __shared__ float W1kg[64], W1vg[64];
    __shared__ __align__(16) float AK[2][512], AV[2][512];

    int t = threadIdx.x;
    int li = t >> 3, g = t & 7;
    int lanebase = (t & 63) & 56;
    {
        const float4* Wg4 = (const float4*)(ws + WS_WC);
        ((float4*)Wc)[t] = Wg4[t];
    }
    if (t < 64) { W1kg[t] = W1_kg[t]; W1vg[t] = W1_vg[t]; }

    int n0 = blockIdx.x * NPT;
    int n = n0 + li;
    int count = NN - n0; if (count > NPT) count = NPT;
    bool valid = li < count;
    float4 fv4 = make_float4(0.f, 0.f, 0.f, 0.f);
    float z = 0.f;
    int b = 0;
    if (valid) {
        b = batch[n];
        fv4 = ((const float4*)nf)[n * 8 + g];
        ((float4*)(Fl + li * 36))[g] = fv4;
        z = pos[3 * n + 2];
        if (g == 0) Lb[li] = b;
    }
    __syncthreads();
    int bf = Lb[0], bl = Lb[count - 1];
    int nseg = (bl != bf) ? 2 : 1;

    // stage AK/AV (float4: 512 f = 128 float4 per slot/array; 256 threads)
    for (int sl = 0; sl < nseg; ++sl) {
        int bb = sl ? bl : bf;
        const float4* Ag = (const float4*)(ws + WS_AKG + bb * 512);
        const float4* Vg = (const float4*)(ws + WS_AVG + bb * 512);
        if (t < 128) ((float4*)AK[sl])[t] = Ag[t];
        else         ((float4*)AV[sl])[t - 128] = Vg[t - 128];
    }
    __syncthreads();

    if (!valid) return;
    int slot = (b == bf) ? 0 : 1;
    const float4* Ak4 = (const float4*)AK[slot];
    const float4* Av4 = (const float4*)AV[slot];
    const float4* Wc4 = (const float4*)Wc;

    float zminb = ws[WS_ZMIN + b];
    float zmaxb = ws[WS_ZMAX + b];
    float edge[2][8];
    bessel_edges(bw[0], z - zminb + DIST_C, zmaxb + DIST_C - z, edge);

    float sk0, sk1, sv0, sv1;
    {
        float pk0 = 0.f, pk1 = 0.f, pv0 = 0.f, pv1 = 0.f;
#pragma unroll
        for (int k = 0; k < 8; ++k) {
            float wk = W1kg[k * 8 + g];
            float wv = W1vg[k * 8 + g];
            pk0 += edge[0][k] * wk; pk1 += edge[1][k] * wk;
            pv0 += edge[0][k] * wv; pv1 += edge[1][k] * wv;
        }
        sk0 = silu(pk0); sk1 = silu(pk1);
        sv0 = silu(pv0); sv1 = silu(pv1);
    }
    float4 q4 = make_float4(0.f, 0.f, 0.f, 0.f);
    const float* myF = Fl + li * 36;
#pragma unroll
    for (int d = 0; d < 32; ++d) {
        float fd = myF[d];
        float4 w = Wc4[d * 8 + g];
        q4.x += fd * w.x; q4.y += fd * w.y; q4.z += fd * w.z; q4.w += fd * w.w;
    }
    float p0 = 0.f, p1 = 0.f;
#pragma unroll
    for (int h = 0; h < 8; ++h) {
        float4 a0 = Ak4[h * 8 + g];
        float4 a1 = Ak4[64 + h * 8 + g];
        float d0 = q4.x * a0.x + q4.y * a0.y + q4.z * a0.z + q4.w * a0.w;
        float d1 = q4.x * a1.x + q4.y * a1.y + q4.z * a1.z + q4.w * a1.w;
        p0 += __shfl(sk0, lanebase + h, 64) * d0;
        p1 += __shfl(sk1, lanebase + h, 64) * d1;
    }
#pragma unroll
    for (int m = 1; m < 8; m <<= 1) {
        p0 += __shfl_xor(p0, m, 64);
        p1 += __shfl_xor(p1, m, 64);
    }
    float sg0 = p0 * SCALE_C, sg1 = p1 * SCALE_C;
    float mx = fmaxf(sg0, sg1);
    float e0 = __expf(sg0 - mx), e1 = __expf(sg1 - mx);
    float inv = 1.0f / (e0 + e1);
    float ag0 = e0 * inv, ag1 = e1 * inv;

    float4 x4 = fv4;
#pragma unroll
    for (int h = 0; h < 8; ++h) {
        float w0 = ag0 * __shfl(sv0, lanebase + h, 64);
        float w1 = ag1 * __shfl(sv1, lanebase + h, 64);
        float4 a0 = Av4[h * 8 + g];
        float4 a1 = Av4[64 + h * 8 + g];
        x4.x += w0 * a0.x + w1 * a1.x;
        x4.y += w0 * a0.y + w1 * a1.y;
        x4.z += w0 * a0.z + w1 * a1.z;
        x4.w += w0 * a0.w + w1 * a1.w;
    }
    ((float4*)out)[n * 8 + g] = x4;
}

extern "C" void kernel_launch(void* const* d_in, const int* in_sizes, int n_in,
                              void* d_out, int out_size, void* d_ws, size_t ws_size,
                              hipStream_t stream) {
    const float* pos        = (const float*)d_in[0];
    const float* nf         = (const float*)d_in[1];
    const int*   batch      = (const int*)d_in[2];
    const float* bw         = (const float*)d_in[3];
    const float* init_dummy = (const float*)d_in[4];
    const float* Wq_dummy   = (const float*)d_in[5];
    const float* Wq_graph   = (const float*)d_in[6];
    const float* Wdot       = (const float*)d_in[7];
    const float* W1_kd      = (const float*)d_in[8];
    const float* W2_kd      = (const float*)d_in[9];
    const float* W1_vd      = (const float*)d_in[10];
    const float* W2_vd      = (const float*)d_in[11];
    const float* W1_kg      = (const float*)d_in[12];
    const float* W2_kg      = (const float*)d_in[13];
    const float* W1_vg      = (const float*)d_in[14];
    const float* W2_vg      = (const float*)d_in[15];
    float* ws  = (float*)d_ws;
    float* out = (float*)d_out;

    int nblk = (NN + NPT - 1) / NPT;   // 938
    hipLaunchKernelGGL(k_pre, dim3(34), dim3(256), 0, stream,
                       pos, batch, init_dummy, Wq_dummy, Wdot, W2_kd, Wq_graph, ws);
    hipLaunchKernelGGL(k_phase1, dim3(nblk), dim3(256), 0, stream,
                       pos, batch, nf, bw, W1_kd, W1_vd, ws);
    hipLaunchKernelGGL(k_batch, dim3(32), dim3(256), 0, stream,
                       init_dummy, W2_vd, W2_kg, W2_vg, ws);
    hipLaunchKernelGGL(k_fin, dim3(nblk), dim3(256), 0, stream,
                       pos, batch, nf, bw, W1_kg, W1_vg, ws, out);
}